// Round 1
// baseline (2438.398 us; speedup 1.0000x reference)
//
#include <hip/hip_runtime.h>
#include <math.h>

#define TT 50
#define BB 256
#define HH 256
#define MSZ 256
#define MDM 64
#define NRD 4
#define NCL 5
#define GAMMA_ 0.95f
#define EPS_ 1e-8f

__device__ __forceinline__ float sigf(float x){ return 1.f/(1.f + expf(-x)); }

// ---------------- K0: init state ----------------
__global__ __launch_bounds__(256) void k_init(float* h, float* c, float* r,
                                              float* wr, float* wu, float* M){
  int i = blockIdx.x*256 + threadIdx.x;          // grid covers exactly 4194304 = B*MS*MD
  M[i] = 1e-6f;
  if (i < BB*HH) { h[i]=0.f; c[i]=0.f; r[i]=0.f; wu[i] = 1.f/256.f; }
  if (i < BB*NRD*MSZ) wr[i] = 1.f/256.f;
}

// ---------------- K1: X_proj = x_seq @ W_ih[:405] + b_lstm  (rows m = t*256+b) ----------------
__global__ __launch_bounds__(256) void k_xproj(
  const float* __restrict__ X, const int* __restrict__ tgt,
  const float* __restrict__ Wih, const float* __restrict__ bl,
  float* __restrict__ Xp)
{
  __shared__ float As[16*68];   // [kk][row], pad 68 (float4-aligned, conflict-free)
  __shared__ float Bs[16*64];   // [kk][col]
  const int tid = threadIdx.x;
  const int m0 = blockIdx.x*64, j0 = blockIdx.y*64;
  const int tx = tid & 15, ty = tid >> 4;
  const int arow = tid >> 2, aseg = tid & 3;
  const int ma = m0 + arow;
  const float* Arow = X + ((ma & 255)*TT + (ma >> 8))*400;   // input_var[b][t][:]
  const int bkr = tid >> 4, bjs = tid & 15;
  float acc[4][4] = {};
  for (int k0 = 0; k0 < 400; k0 += 16) {      // 400 = 25*16 exact
    float4 av = *(const float4*)(Arow + k0 + aseg*4);
    float4 bv = *(const float4*)(Wih + (k0 + bkr)*1024 + j0 + bjs*4);
    __syncthreads();
    As[(aseg*4+0)*68 + arow] = av.x;
    As[(aseg*4+1)*68 + arow] = av.y;
    As[(aseg*4+2)*68 + arow] = av.z;
    As[(aseg*4+3)*68 + arow] = av.w;
    *(float4*)&Bs[bkr*64 + bjs*4] = bv;
    __syncthreads();
#pragma unroll
    for (int kk = 0; kk < 16; ++kk) {
      float4 a4 = *(const float4*)&As[kk*68 + ty*4];
      float4 b4 = *(const float4*)&Bs[kk*64 + tx*4];
      acc[0][0] = fmaf(a4.x,b4.x,acc[0][0]); acc[0][1] = fmaf(a4.x,b4.y,acc[0][1]);
      acc[0][2] = fmaf(a4.x,b4.z,acc[0][2]); acc[0][3] = fmaf(a4.x,b4.w,acc[0][3]);
      acc[1][0] = fmaf(a4.y,b4.x,acc[1][0]); acc[1][1] = fmaf(a4.y,b4.y,acc[1][1]);
      acc[1][2] = fmaf(a4.y,b4.z,acc[1][2]); acc[1][3] = fmaf(a4.y,b4.w,acc[1][3]);
      acc[2][0] = fmaf(a4.z,b4.x,acc[2][0]); acc[2][1] = fmaf(a4.z,b4.y,acc[2][1]);
      acc[2][2] = fmaf(a4.z,b4.z,acc[2][2]); acc[2][3] = fmaf(a4.z,b4.w,acc[2][3]);
      acc[3][0] = fmaf(a4.w,b4.x,acc[3][0]); acc[3][1] = fmaf(a4.w,b4.y,acc[3][1]);
      acc[3][2] = fmaf(a4.w,b4.z,acc[3][2]); acc[3][3] = fmaf(a4.w,b4.w,acc[3][3]);
    }
  }
#pragma unroll
  for (int i = 0; i < 4; ++i){
    int m = m0 + ty*4 + i;
    int t = m >> 8, b = m & 255;
    const float* offrow = (t > 0) ? (Wih + (400 + tgt[b*TT + t - 1])*1024) : nullptr;
    int cj = j0 + tx*4;
    float4 r4;
    r4.x = acc[i][0] + bl[cj+0] + (offrow ? offrow[cj+0] : 0.f);
    r4.y = acc[i][1] + bl[cj+1] + (offrow ? offrow[cj+1] : 0.f);
    r4.z = acc[i][2] + bl[cj+2] + (offrow ? offrow[cj+2] : 0.f);
    r4.w = acc[i][3] + bl[cj+3] + (offrow ? offrow[cj+3] : 0.f);
    *(float4*)&Xp[m*1024 + cj] = r4;
  }
}

// ---------------- K2a: split-K recurrent GEMM  gates_part[p] = [r|h] @ [W_ih[405:];W_hh] ----------------
__global__ __launch_bounds__(256) void k_rgemm(
  const float* __restrict__ rst, const float* __restrict__ hst,
  const float* __restrict__ Wih, const float* __restrict__ Whh,
  float* __restrict__ gp)
{
  __shared__ float As[16*68];
  __shared__ float Bs[16*64];
  const int tid = threadIdx.x;
  const int m0 = blockIdx.x*64, j0 = blockIdx.y*64, p = blockIdx.z;
  const int tx = tid & 15, ty = tid >> 4;
  const int arow = tid >> 2, aseg = tid & 3;
  const int bkr = tid >> 4, bjs = tid & 15;
  float acc[4][4] = {};
  const int kbase = p*128;
  for (int k0 = kbase; k0 < kbase + 128; k0 += 16) {
    int ka = k0 + aseg*4;
    const float* asrc = (ka < 256) ? (rst + (m0+arow)*256 + ka)
                                   : (hst + (m0+arow)*256 + ka - 256);
    float4 av = *(const float4*)asrc;
    int kb = k0 + bkr;
    const float* bsrc = (kb < 256) ? (Wih + (405 + kb)*1024) : (Whh + (kb - 256)*1024);
    float4 bv = *(const float4*)(bsrc + j0 + bjs*4);
    __syncthreads();
    As[(aseg*4+0)*68 + arow] = av.x;
    As[(aseg*4+1)*68 + arow] = av.y;
    As[(aseg*4+2)*68 + arow] = av.z;
    As[(aseg*4+3)*68 + arow] = av.w;
    *(float4*)&Bs[bkr*64 + bjs*4] = bv;
    __syncthreads();
#pragma unroll
    for (int kk = 0; kk < 16; ++kk) {
      float4 a4 = *(const float4*)&As[kk*68 + ty*4];
      float4 b4 = *(const float4*)&Bs[kk*64 + tx*4];
      acc[0][0] = fmaf(a4.x,b4.x,acc[0][0]); acc[0][1] = fmaf(a4.x,b4.y,acc[0][1]);
      acc[0][2] = fmaf(a4.x,b4.z,acc[0][2]); acc[0][3] = fmaf(a4.x,b4.w,acc[0][3]);
      acc[1][0] = fmaf(a4.y,b4.x,acc[1][0]); acc[1][1] = fmaf(a4.y,b4.y,acc[1][1]);
      acc[1][2] = fmaf(a4.y,b4.z,acc[1][2]); acc[1][3] = fmaf(a4.y,b4.w,acc[1][3]);
      acc[2][0] = fmaf(a4.z,b4.x,acc[2][0]); acc[2][1] = fmaf(a4.z,b4.y,acc[2][1]);
      acc[2][2] = fmaf(a4.z,b4.z,acc[2][2]); acc[2][3] = fmaf(a4.z,b4.w,acc[2][3]);
      acc[3][0] = fmaf(a4.w,b4.x,acc[3][0]); acc[3][1] = fmaf(a4.w,b4.y,acc[3][1]);
      acc[3][2] = fmaf(a4.w,b4.z,acc[3][2]); acc[3][3] = fmaf(a4.w,b4.w,acc[3][3]);
    }
  }
  float* outp = gp + p*(BB*1024);
#pragma unroll
  for (int i = 0; i < 4; ++i){
    int bb = m0 + ty*4 + i;
    *(float4*)&outp[bb*1024 + j0 + tx*4] =
      make_float4(acc[i][0], acc[i][1], acc[i][2], acc[i][3]);
  }
}

// ---------------- K2b: LSTM pointwise ----------------
__global__ __launch_bounds__(256) void k_lstm(
  const float* __restrict__ Xp, const float* __restrict__ gp,
  float* __restrict__ h, float* __restrict__ c, float* __restrict__ outs, int t)
{
  const int b = blockIdx.x, i = threadIdx.x;
  const float* xr = Xp + (t*256 + b)*1024;
  const float* g0 = gp + b*1024;
  float g[4];
#pragma unroll
  for (int q = 0; q < 4; ++q){
    int col = q*256 + i;
    g[q] = xr[col] + g0[col] + g0[262144 + col] + g0[2*262144 + col] + g0[3*262144 + col];
  }
  float cn = sigf(g[1])*c[b*256+i] + sigf(g[0])*tanhf(g[2]);
  float hn = sigf(g[3])*tanhf(cn);
  c[b*256+i] = cn; h[b*256+i] = hn;
  outs[(b*TT + t)*512 + i] = hn;
}

// ---------------- K3: keys + LRUA memory update (one block per batch) ----------------
__global__ __launch_bounds__(256) void k_mem(
  const float* __restrict__ Wkp, const float* __restrict__ bkp,
  const float* __restrict__ h, float* __restrict__ rst,
  float* __restrict__ wr_g, float* __restrict__ wu_g,
  float* __restrict__ Mg, float* __restrict__ outs, int t)
{
  extern __shared__ float sm[];
  float* Ms   = sm;             // 256*65 = 16640
  float* wrL  = sm + 16640;     // 1024
  float* wwL  = wrL + 1024;     // 1024
  float* simL = wwL + 1024;     // 1024
  float* wuL  = simL + 1024;    // 256
  float* kL   = wuL + 256;      // 256
  float* hL   = kL + 256;       // 256   -> total 20480 floats = 81920 B
  __shared__ unsigned long long redU[4];
  __shared__ int luS[4];
  __shared__ float alphaS[4];
  __shared__ float kinv[4];

  const int b = blockIdx.x, tid = threadIdx.x;
  hL[tid]  = h[b*256 + tid];
  wuL[tid] = wu_g[b*256 + tid];
  *(float4*)&wrL[tid*4] = *(const float4*)&wr_g[b*1024 + tid*4];
  const float4* Mg4 = (const float4*)(Mg + (size_t)b*(MSZ*MDM));
#pragma unroll
  for (int it = 0; it < 16; ++it){            // stage M -> LDS (padded rows)
    int i4 = it*256 + tid;
    int n = i4 >> 4, d4 = (i4 & 15) << 2;
    float4 v = Mg4[i4];
    float* pp = Ms + n*65 + d4;
    pp[0]=v.x; pp[1]=v.y; pp[2]=v.z; pp[3]=v.w;
  }
  __syncthreads();
  // key projection p = h @ W_kp + b_kp ; k=tanh, alpha=sigmoid
  for (int j = tid; j < 260; j += 256){
    float acc = bkp[j];
    for (int k = 0; k < 256; ++k) acc = fmaf(hL[k], Wkp[k*260 + j], acc);
    if (j < 256) kL[j] = tanhf(acc);
    else alphaS[j-256] = sigf(acc);
  }
  __syncthreads();
  if (tid < 4){
    float s = 0.f;
    for (int d = 0; d < 64; ++d){ float v = kL[tid*64+d]; s = fmaf(v,v,s); }
    kinv[tid] = 1.f/(sqrtf(s) + EPS_);
  }
  // top-4 argmin of w_u, ties -> lowest index (w_u > 0 so bits preserve order)
  unsigned long long mykey =
      (((unsigned long long)__float_as_uint(wuL[tid])) << 32) | (unsigned)tid;
  for (int round = 0; round < 4; ++round){
    __syncthreads();
    unsigned long long key = mykey;
    for (int rr = 0; rr < round; ++rr) if (luS[rr] == tid) key = ~0ull;
    for (int o = 32; o; o >>= 1){
      unsigned long long other = __shfl_xor(key, o, 64);
      if (other < key) key = other;
    }
    if ((tid & 63) == 0) redU[tid >> 6] = key;
    __syncthreads();
    if (tid == 0){
      unsigned long long k0 = redU[0];
      if (redU[1] < k0) k0 = redU[1];
      if (redU[2] < k0) k0 = redU[2];
      if (redU[3] < k0) k0 = redU[3];
      luS[round] = (int)(unsigned)(k0 & 0xffffffffull);
    }
  }
  __syncthreads();
  // write weights  w_w = alpha*w_r + (1-alpha)*onehot(lu)
#pragma unroll
  for (int r = 0; r < 4; ++r){
    float a = alphaS[r];
    float w = a * wrL[r*256 + tid];
    if (tid == luS[r]) w += 1.f - a;
    wwL[r*256 + tid] = w;
  }
  __syncthreads();
  // erase lu[0] row, additive write, row norm + cosine sim (thread = slot)
  {
    const int n = tid;
    float w0 = wwL[n], w1 = wwL[256+n], w2 = wwL[512+n], w3 = wwL[768+n];
    const bool er = (n == luS[0]);
    float* row = Ms + n*65;
    float nsq = 0.f, s0 = 0.f, s1 = 0.f, s2 = 0.f, s3 = 0.f;
#pragma unroll
    for (int d = 0; d < 64; ++d){
      float m = er ? 0.f : row[d];
      m = fmaf(w0, kL[d],     m);
      m = fmaf(w1, kL[64+d],  m);
      m = fmaf(w2, kL[128+d], m);
      m = fmaf(w3, kL[192+d], m);
      row[d] = m;
      nsq = fmaf(m, m, nsq);
      s0 = fmaf(kL[d],     m, s0);
      s1 = fmaf(kL[64+d],  m, s1);
      s2 = fmaf(kL[128+d], m, s2);
      s3 = fmaf(kL[192+d], m, s3);
    }
    float minv = 1.f/(sqrtf(nsq) + EPS_);
    simL[n]     = s0 * kinv[0] * minv;
    simL[256+n] = s1 * kinv[1] * minv;
    simL[512+n] = s2 * kinv[2] * minv;
    simL[768+n] = s3 * kinv[3] * minv;
  }
  __syncthreads();
  // softmax over slots, one wave per read head
  {
    const int r = tid >> 6, l = tid & 63;
    float v0 = simL[r*256 + l],       v1 = simL[r*256 + 64 + l],
          v2 = simL[r*256 + 128 + l], v3 = simL[r*256 + 192 + l];
    float mx = fmaxf(fmaxf(v0,v1), fmaxf(v2,v3));
    for (int o = 32; o; o >>= 1) mx = fmaxf(mx, __shfl_xor(mx, o, 64));
    float e0 = expf(v0-mx), e1 = expf(v1-mx), e2 = expf(v2-mx), e3 = expf(v3-mx);
    float s = e0+e1+e2+e3;
    for (int o = 32; o; o >>= 1) s += __shfl_xor(s, o, 64);
    float inv = 1.f/s;
    e0 *= inv; e1 *= inv; e2 *= inv; e3 *= inv;
    wrL[r*256 + l] = e0; wrL[r*256 + 64 + l] = e1;
    wrL[r*256 + 128 + l] = e2; wrL[r*256 + 192 + l] = e3;
    wr_g[b*1024 + r*256 + l]       = e0;
    wr_g[b*1024 + r*256 + 64 + l]  = e1;
    wr_g[b*1024 + r*256 + 128 + l] = e2;
    wr_g[b*1024 + r*256 + 192 + l] = e3;
  }
  __syncthreads();
  // reads = w_r @ M  (thread = (r,d))
  {
    const int r = tid >> 6, d = tid & 63;
    float acc = 0.f;
    for (int n = 0; n < 256; ++n) acc = fmaf(wrL[r*256+n], Ms[n*65+d], acc);
    outs[(b*TT + t)*512 + 256 + tid] = acc;
    rst[b*256 + tid] = acc;
  }
  // usage update
  {
    float wu = GAMMA_*wuL[tid]
      + wrL[tid] + wrL[256+tid] + wrL[512+tid] + wrL[768+tid]
      + wwL[tid] + wwL[256+tid] + wwL[512+tid] + wwL[768+tid];
    wu_g[b*256 + tid] = wu;
  }
  // M write-back
  float4* Mw4 = (float4*)(Mg + (size_t)b*(MSZ*MDM));
#pragma unroll
  for (int it = 0; it < 16; ++it){
    int i4 = it*256 + tid;
    int n = i4 >> 4, d4 = (i4 & 15) << 2;
    const float* pp = Ms + n*65 + d4;
    Mw4[i4] = make_float4(pp[0], pp[1], pp[2], pp[3]);
  }
}

// ---------------- K4: logits + softmax (one wave per (b,t) row) ----------------
__global__ __launch_bounds__(256) void k_out(
  const float* __restrict__ outs, const float* __restrict__ Wout,
  const float* __restrict__ bout, float* __restrict__ out)
{
  const int m = blockIdx.x*4 + (threadIdx.x >> 6);
  const int l = threadIdx.x & 63;
  const float* row = outs + m*512;
  float a0=0,a1=0,a2=0,a3=0,a4=0;
#pragma unroll
  for (int q = 0; q < 8; ++q){
    int e = q*64 + l;
    float v = row[e];
    const float* w = Wout + e*5;
    a0 = fmaf(v,w[0],a0); a1 = fmaf(v,w[1],a1); a2 = fmaf(v,w[2],a2);
    a3 = fmaf(v,w[3],a3); a4 = fmaf(v,w[4],a4);
  }
  for (int o = 32; o; o >>= 1){
    a0 += __shfl_xor(a0,o,64); a1 += __shfl_xor(a1,o,64); a2 += __shfl_xor(a2,o,64);
    a3 += __shfl_xor(a3,o,64); a4 += __shfl_xor(a4,o,64);
  }
  if (l == 0){
    float l0=a0+bout[0], l1=a1+bout[1], l2=a2+bout[2], l3=a3+bout[3], l4=a4+bout[4];
    float mx = fmaxf(fmaxf(fmaxf(l0,l1),fmaxf(l2,l3)),l4);
    float e0=expf(l0-mx),e1=expf(l1-mx),e2=expf(l2-mx),e3=expf(l3-mx),e4=expf(l4-mx);
    float inv = 1.f/(e0+e1+e2+e3+e4);
    float* o5 = out + m*5;
    o5[0]=e0*inv; o5[1]=e1*inv; o5[2]=e2*inv; o5[3]=e3*inv; o5[4]=e4*inv;
  }
}

extern "C" void kernel_launch(void* const* d_in, const int* in_sizes, int n_in,
                              void* d_out, int out_size, void* d_ws, size_t ws_size,
                              hipStream_t stream)
{
  (void)in_sizes; (void)n_in; (void)out_size; (void)ws_size;
  const float* X    = (const float*)d_in[0];
  const int*   tgt  = (const int*)d_in[1];
  const float* Wih  = (const float*)d_in[2];
  const float* Whh  = (const float*)d_in[3];
  const float* bl   = (const float*)d_in[4];
  const float* Wkp  = (const float*)d_in[5];
  const float* bkp  = (const float*)d_in[6];
  const float* Wout = (const float*)d_in[7];
  const float* bout = (const float*)d_in[8];
  float* out = (float*)d_out;

  float* ws   = (float*)d_ws;
  float* Xp   = ws;                    // 13,107,200 floats  [T*B, 1024]
  float* outs = Xp + 13107200;         //  6,553,600         [B*T, 512]
  float* gp   = outs + 6553600;        //  1,048,576         [4][B,1024] split-K partials
  float* hst  = gp + 1048576;          //     65,536
  float* cst  = hst + 65536;           //     65,536
  float* rstt = cst + 65536;           //     65,536
  float* wrg  = rstt + 65536;          //    262,144         [B,4,256]
  float* wug  = wrg + 262144;          //     65,536
  float* Mg   = wug + 65536;           //  4,194,304         [B,256,64]

  hipFuncSetAttribute(reinterpret_cast<const void*>(k_mem),
                      hipFuncAttributeMaxDynamicSharedMemorySize, 81920);

  k_init<<<16384, 256, 0, stream>>>(hst, cst, rstt, wrg, wug, Mg);
  k_xproj<<<dim3(200,16), 256, 0, stream>>>(X, tgt, Wih, bl, Xp);
  for (int t = 0; t < TT; ++t){
    k_rgemm<<<dim3(4,16,4), 256, 0, stream>>>(rstt, hst, Wih, Whh, gp);
    k_lstm<<<256, 256, 0, stream>>>(Xp, gp, hst, cst, outs, t);
    k_mem<<<256, 256, 81920, stream>>>(Wkp, bkp, hst, rstt, wrg, wug, Mg, outs, t);
  }
  k_out<<<3200, 256, 0, stream>>>(outs, Wout, bout, out);
}